// Round 4
// baseline (414.011 us; speedup 1.0000x reference)
//
#include <hip/hip_runtime.h>
#include <stdint.h>

#define S_LEN 2048
#define HIDDEN 1024
#define NHEADS 16
#define NKVH 4
#define HDIM 64

typedef __bf16 bf16x8 __attribute__((ext_vector_type(8)));
typedef float f32x4 __attribute__((ext_vector_type(4)));
typedef unsigned short ushortx8 __attribute__((ext_vector_type(8)));
typedef short s16x4 __attribute__((ext_vector_type(4)));
typedef unsigned short U16;

// ---- workspace layout (bf16 elems) -----------------------------------------
#define OFF_XB   0u          // 8192*1024 (aliased by aws later)
#define OFF_WQB  8388608u
#define OFF_WKB  9437184u
#define OFF_WVB  9699328u
#define OFF_WOB  9961472u
#define OFF_Q    11010048u
#define OFF_K    19398656u
#define OFF_V    21495808u
#define OFF_AWS  OFF_XB

static __device__ __forceinline__ U16 f2bf(float f){
    unsigned u;
    __builtin_memcpy(&u, &f, 4);
    u += 0x7FFFu + ((u >> 16) & 1u);   // RNE
    return (U16)(u >> 16);
}
static __device__ __forceinline__ uint32_t pkbf(float lo, float hi){
    uint32_t a, b;
    __builtin_memcpy(&a, &lo, 4); a += 0x7FFFu + ((a >> 16) & 1u);
    __builtin_memcpy(&b, &hi, 4); b += 0x7FFFu + ((b >> 16) & 1u);
    return (a >> 16) | (b & 0xFFFF0000u);
}

typedef __attribute__((address_space(3))) uint32_t lds_u32;
typedef const __attribute__((address_space(1))) uint32_t glb_u32;
static __device__ __forceinline__ void glds16(const U16* g, U16* l){
    __builtin_amdgcn_global_load_lds((glb_u32*)g, (lds_u32*)l, 16, 0, 0);
}

// ---------------------------------------------------------------------------
// Kernel 0: fp32 -> bf16 convert of X, Wq, Wk, Wv, Wo into workspace.
// ---------------------------------------------------------------------------
__global__ void conv_kernel(const float* __restrict__ X,  const float* __restrict__ Wq,
                            const float* __restrict__ Wk, const float* __restrict__ Wv,
                            const float* __restrict__ Wo, U16* __restrict__ dst)
{
    size_t i4 = (size_t)blockIdx.x * 256 + threadIdx.x;
    size_t e = i4 * 4;
    const float* s;
    if (e < 8388608u)       s = X  + e;
    else if (e < 9437184u)  s = Wq + (e - 8388608u);
    else if (e < 9699328u)  s = Wk + (e - 9437184u);
    else if (e < 9961472u)  s = Wv + (e - 9699328u);
    else                    s = Wo + (e - 9961472u);
    float4 v = *(const float4*)s;
    uint2 o; o.x = pkbf(v.x, v.y); o.y = pkbf(v.z, v.w);
    *(uint2*)(dst + e) = o;
}

// ---------------------------------------------------------------------------
// Kernel 1: QKV GEMM (NT) + bias + RoPE. BK=64, glds16 staging. grid (12,64).
// Q is pre-scaled by 0.125*log2(e) so attention softmax runs in exp2 domain.
// ---------------------------------------------------------------------------
__global__ __launch_bounds__(256, 3)
void qkv_kernel(const U16* __restrict__ Xb,
                const U16* __restrict__ Wqb, const U16* __restrict__ Wkb, const U16* __restrict__ Wvb,
                const float* __restrict__ bq, const float* __restrict__ bk, const float* __restrict__ bv,
                const float* __restrict__ cosT, const float* __restrict__ sinT,
                U16* __restrict__ qws, U16* __restrict__ kws, U16* __restrict__ vws)
{
    __shared__ __align__(16) U16 Asm[128 * 64];   // 16 KB
    __shared__ __align__(16) U16 Bsm[128 * 64];

    const int nblk = blockIdx.x;
    const int mblk = blockIdx.y;
    const int tid  = threadIdx.x;
    const int wave = tid >> 6, lane = tid & 63;
    const int ln = lane & 15, quad = lane >> 4;
    const int wm = wave >> 1, wn = wave & 1;

    const U16* Wp; const float* biasp; int region;
    const int nbase = nblk * 128;
    if (nblk < 8)       { Wp = Wqb + (size_t)nbase * HIDDEN;          biasp = bq + nbase;          region = 0; }
    else if (nblk < 10) { Wp = Wkb + (size_t)(nbase - 1024) * HIDDEN; biasp = bk + (nbase - 1024); region = 1; }
    else                { Wp = Wvb + (size_t)(nbase - 1280) * HIDDEN; biasp = bv + (nbase - 1280); region = 2; }
    const U16* Xp = Xb + (size_t)mblk * 128 * HIDDEN;

    f32x4 acc[4][4];
    #pragma unroll
    for (int i = 0; i < 4; i++)
        #pragma unroll
        for (int j = 0; j < 4; j++) acc[i][j] = (f32x4){0.f, 0.f, 0.f, 0.f};

    const int lrow = lane >> 3;          // 0..7
    const int lcol = (lane & 7) * 8;     // 0..56

    for (int k0 = 0; k0 < HIDDEN; k0 += 64) {
        __syncthreads();
        #pragma unroll
        for (int t = 0; t < 4; t++) {
            int rbase = wave * 32 + t * 8;
            glds16(Xp + (size_t)(rbase + lrow) * HIDDEN + k0 + lcol, &Asm[rbase * 64]);
            glds16(Wp + (size_t)(rbase + lrow) * HIDDEN + k0 + lcol, &Bsm[rbase * 64]);
        }
        __syncthreads();

        bf16x8 af[4][2], bfr[4][2];
        #pragma unroll
        for (int i = 0; i < 4; i++)
            #pragma unroll
            for (int ks = 0; ks < 2; ks++) {
                af[i][ks]  = *(const bf16x8*)(&Asm[(wm * 64 + i * 16 + ln) * 64 + ks * 32 + quad * 8]);
                bfr[i][ks] = *(const bf16x8*)(&Bsm[(wn * 64 + i * 16 + ln) * 64 + ks * 32 + quad * 8]);
            }
        #pragma unroll
        for (int i = 0; i < 4; i++)
            #pragma unroll
            for (int j = 0; j < 4; j++) {
                acc[i][j] = __builtin_amdgcn_mfma_f32_16x16x32_bf16(af[i][0], bfr[j][0], acc[i][j], 0, 0, 0);
                acc[i][j] = __builtin_amdgcn_mfma_f32_16x16x32_bf16(af[i][1], bfr[j][1], acc[i][j], 0, 0, 0);
            }
    }

    float bias[4];
    #pragma unroll
    for (int j = 0; j < 4; j++) bias[j] = biasp[wn * 64 + j * 16 + ln];

    const float QSCALE = 0.125f * 1.44269504089f;   // fold softmax scale + log2(e)

    #pragma unroll
    for (int i = 0; i < 4; i++) {
        #pragma unroll
        for (int r = 0; r < 4; r++) {
            int m = mblk * 128 + wm * 64 + i * 16 + quad * 4 + r;
            int s = m & (S_LEN - 1), b = m >> 11;
            float vals[4];
            #pragma unroll
            for (int j = 0; j < 4; j++) vals[j] = acc[i][j][r] + bias[j];

            if (region == 2) {      // V
                #pragma unroll
                for (int j = 0; j < 4; j++) {
                    int n2 = nbase - 1280 + wn * 64 + j * 16 + ln;
                    int hh = n2 >> 6, d = n2 & 63;
                    vws[(((size_t)b * NKVH + hh) * S_LEN + s) * HDIM + d] = f2bf(vals[j]);
                }
            } else {
                float outv[4];
                #pragma unroll
                for (int j = 0; j < 4; j++) {
                    int d = (wn * 64 + j * 16 + ln) & 63;
                    float c  = cosT[s * HDIM + d];
                    float sn = sinT[s * HDIM + d];
                    float partner = vals[j ^ 2];
                    float rot = (d < 32) ? -partner : partner;
                    outv[j] = vals[j] * c + rot * sn;
                }
                if (region == 0) {  // Q (scaled)
                    #pragma unroll
                    for (int j = 0; j < 4; j++) {
                        int n = nbase + wn * 64 + j * 16 + ln;
                        int hh = n >> 6, d = n & 63;
                        qws[(((size_t)b * NHEADS + hh) * S_LEN + s) * HDIM + d] = f2bf(outv[j] * QSCALE);
                    }
                } else {            // K
                    #pragma unroll
                    for (int j = 0; j < 4; j++) {
                        int n2 = nbase - 1024 + wn * 64 + j * 16 + ln;
                        int hh = n2 >> 6, d = n2 & 63;
                        kws[(((size_t)b * NKVH + hh) * S_LEN + s) * HDIM + d] = f2bf(outv[j]);
                    }
                }
            }
        }
    }
}

// ---------------------------------------------------------------------------
// Kernel 2: flash attention. S^T = K*Q^T (16x16x32, K-frags direct from
// global/L2). PV via 16x16x16 MFMA: packed score pairs ARE the B-fragment
// (C-layout key=quad*4+r == B-layout k=quad*4+j). No P repack, no Ksm.
// Double-buffered V^T in LDS -> ONE barrier per K-tile. grid (16, 64).
// ---------------------------------------------------------------------------
#define A_VTS 136   // V^T LDS stride (elems)

__global__ __launch_bounds__(256, 3)
void attn_kernel(const U16* __restrict__ qws, const U16* __restrict__ kws,
                 const U16* __restrict__ vws, U16* __restrict__ aws)
{
    __shared__ __align__(16) U16 VTsm[2][64 * A_VTS];   // 34816 B total

    const int qt = blockIdx.x;
    const int hg = blockIdx.y;
    const int b = hg >> 4, h = hg & 15, hkv = h >> 2;
    const U16* Qh = qws + (size_t)hg * S_LEN * HDIM;
    const U16* Kh = kws + (size_t)(b * NKVH + hkv) * S_LEN * HDIM;
    const U16* Vh = vws + (size_t)(b * NKVH + hkv) * S_LEN * HDIM;

    const int tid = threadIdx.x;
    const int wave = tid >> 6, lane = tid & 63;
    const int ln = lane & 15, quad = lane >> 4;

    // Q fragments (B-operand, resident): q = qt*128 + wave*32 + 16i + ln
    bf16x8 qf[2][2];
    #pragma unroll
    for (int i = 0; i < 2; i++)
        #pragma unroll
        for (int ks = 0; ks < 2; ks++) {
            int row = qt * 128 + wave * 32 + i * 16 + ln;
            qf[i][ks] = *(const bf16x8*)(Qh + (size_t)row * HDIM + ks * 32 + quad * 8);
        }

    float mi[2] = {-1e30f, -1e30f}, li[2] = {0.f, 0.f};
    f32x4 o_t[4][2];   // O^T[d-block n][q-block i]
    #pragma unroll
    for (int n = 0; n < 4; n++)
        #pragma unroll
        for (int i = 0; i < 2; i++) o_t[n][i] = (f32x4){0.f, 0.f, 0.f, 0.f};

    // V prefetch (rows of V, transposed into LDS at store time)
    ushortx8 vreg[4];
    #pragma unroll
    for (int it = 0; it < 4; it++) {
        int idx = tid + it * 256;
        vreg[it] = *(const ushortx8*)(Vh + (size_t)(idx & 127) * HDIM + ((idx >> 7) * 8));
    }

    int p = 0;
    for (int kt = 0; kt < 16; kt++) {
        // scatter current V tile into VTsm[p]
        #pragma unroll
        for (int it = 0; it < 4; it++) {
            int idx = tid + it * 256;
            int sv = idx & 127, d0 = (idx >> 7) * 8;
            #pragma unroll
            for (int jj = 0; jj < 8; jj++) VTsm[p][(d0 + jj) * A_VTS + sv] = vreg[it][jj];
        }
        // prefetch next V tile
        if (kt < 15) {
            #pragma unroll
            for (int it = 0; it < 4; it++) {
                int idx = tid + it * 256;
                vreg[it] = *(const ushortx8*)(Vh + (size_t)((kt + 1) * 128 + (idx & 127)) * HDIM + ((idx >> 7) * 8));
            }
        }
        __syncthreads();   // VTsm[p] complete (writes to [p^1] next iter can't clash)

        #pragma unroll
        for (int h2 = 0; h2 < 2; h2++) {
            // ---- S^T = K*Q^T for 64 keys (4 j-blocks of 16)
            f32x4 st[2][4];
            #pragma unroll
            for (int j4 = 0; j4 < 4; j4++) {
                int krow = kt * 128 + (h2 * 4 + j4) * 16 + ln;
                bf16x8 kf0 = *(const bf16x8*)(Kh + (size_t)krow * HDIM + quad * 8);
                bf16x8 kf1 = *(const bf16x8*)(Kh + (size_t)krow * HDIM + 32 + quad * 8);
                #pragma unroll
                for (int i = 0; i < 2; i++) {
                    f32x4 z = (f32x4){0.f, 0.f, 0.f, 0.f};
                    z = __builtin_amdgcn_mfma_f32_16x16x32_bf16(kf0, qf[i][0], z, 0, 0, 0);
                    z = __builtin_amdgcn_mfma_f32_16x16x32_bf16(kf1, qf[i][1], z, 0, 0, 0);
                    st[i][j4] = z;
                }
            }
            // ---- online softmax (exp2 domain; per-lane rows q = 16i+ln)
            uint32_t pk[2][4][2];
            #pragma unroll
            for (int i = 0; i < 2; i++) {
                float v = st[i][0][0];
                #pragma unroll
                for (int j4 = 0; j4 < 4; j4++)
                    #pragma unroll
                    for (int r = 0; r < 4; r++) v = fmaxf(v, st[i][j4][r]);
                v = fmaxf(v, __shfl_xor(v, 16));
                v = fmaxf(v, __shfl_xor(v, 32));
                float mnew = fmaxf(mi[i], v);
                float alpha = __builtin_amdgcn_exp2f(mi[i] - mnew);
                mi[i] = mnew;
                float rs = 0.f;
                #pragma unroll
                for (int j4 = 0; j4 < 4; j4++)
                    #pragma unroll
                    for (int r = 0; r < 4; r++) {
                        float pv = __builtin_amdgcn_exp2f(st[i][j4][r] - mnew);
                        st[i][j4][r] = pv;
                        rs += pv;
                    }
                rs += __shfl_xor(rs, 16);
                rs += __shfl_xor(rs, 32);
                li[i] = li[i] * alpha + rs;
                #pragma unroll
                for (int n = 0; n < 4; n++) o_t[n][i] *= alpha;
                #pragma unroll
                for (int j4 = 0; j4 < 4; j4++) {
                    pk[i][j4][0] = pkbf(st[i][j4][0], st[i][j4][1]);
                    pk[i][j4][1] = pkbf(st[i][j4][2], st[i][j4][3]);
                }
            }
            // ---- O^T += V^T * P^T via 16x16x16 (B-frag = packed scores, no repack)
            #pragma unroll
            for (int j4 = 0; j4 < 4; j4++) {
                int c = h2 * 4 + j4;   // 16-key chunk
                s16x4 pf[2];
                #pragma unroll
                for (int i = 0; i < 2; i++) __builtin_memcpy(&pf[i], pk[i][j4], 8);
                #pragma unroll
                for (int n = 0; n < 4; n++) {
                    s16x4 vf = *(const s16x4*)(&VTsm[p][(n * 16 + ln) * A_VTS + c * 16 + quad * 4]);
                    #pragma unroll
                    for (int i = 0; i < 2; i++)
                        o_t[n][i] = __builtin_amdgcn_mfma_f32_16x16x16bf16_1k(vf, pf[i], o_t[n][i], 0, 0, 0);
                }
            }
        }
        p ^= 1;
    }

    // epilogue: normalize, write O (8B stores)
    float inv_li[2] = {1.f / li[0], 1.f / li[1]};
    #pragma unroll
    for (int n = 0; n < 4; n++)
        #pragma unroll
        for (int i = 0; i < 2; i++) {
            int q = qt * 128 + wave * 32 + i * 16 + ln;
            int d = n * 16 + quad * 4;
            uint2 w;
            w.x = pkbf(o_t[n][i][0] * inv_li[i], o_t[n][i][1] * inv_li[i]);
            w.y = pkbf(o_t[n][i][2] * inv_li[i], o_t[n][i][3] * inv_li[i]);
            *(uint2*)(aws + ((size_t)b * S_LEN + q) * (NHEADS * HDIM) + h * HDIM + d) = w;
        }
}

// ---------------------------------------------------------------------------
// Kernel 3: output projection GEMM (NT) + bias. BK=64. grid (8, 64). fp32 out.
// ---------------------------------------------------------------------------
__global__ __launch_bounds__(256, 3)
void proj_kernel(const U16* __restrict__ A, const U16* __restrict__ Wob,
                 const float* __restrict__ bo, float* __restrict__ out)
{
    __shared__ __align__(16) U16 Asm[128 * 64];
    __shared__ __align__(16) U16 Bsm[128 * 64];

    const int nblk = blockIdx.x;
    const int mblk = blockIdx.y;
    const int tid  = threadIdx.x;
    const int wave = tid >> 6, lane = tid & 63;
    const int ln = lane & 15, quad = lane >> 4;
    const int wm = wave >> 1, wn = wave & 1;

    const int nbase = nblk * 128;
    const U16* Wp = Wob + (size_t)nbase * HIDDEN;
    const U16* Ap = A + (size_t)mblk * 128 * HIDDEN;

    f32x4 acc[4][4];
    #pragma unroll
    for (int i = 0; i < 4; i++)
        #pragma unroll
        for (int j = 0; j < 4; j++) acc[i][j] = (f32x4){0.f, 0.f, 0.f, 0.f};

    const int lrow = lane >> 3;
    const int lcol = (lane & 7) * 8;

    for (int k0 = 0; k0 < HIDDEN; k0 += 64) {
        __syncthreads();
        #pragma unroll
        for (int t = 0; t < 4; t++) {
            int rbase = wave * 32 + t * 8;
            glds16(Ap + (size_t)(rbase + lrow) * HIDDEN + k0 + lcol, &Asm[rbase * 64]);
            glds16(Wp + (size_t)(rbase + lrow) * HIDDEN + k0 + lcol, &Bsm[rbase * 64]);
        }
        __syncthreads();

        bf16x8 af[4][2], bfr[4][2];
        #pragma unroll
        for (int i = 0; i < 4; i++)
            #pragma unroll
            for (int ks = 0; ks < 2; ks++) {
                af[i][ks]  = *(const bf16x8*)(&Asm[(wm * 64 + i * 16 + ln) * 64 + ks * 32 + quad * 8]);
                bfr[i][ks] = *(const bf16x8*)(&Bsm[(wn * 64 + i * 16 + ln) * 64 + ks * 32 + quad * 8]);
            }
        #pragma unroll
        for (int i = 0; i < 4; i++)
            #pragma unroll
            for (int j = 0; j < 4; j++) {
                acc[i][j] = __builtin_amdgcn_mfma_f32_16x16x32_bf16(af[i][0], bfr[j][0], acc[i][j], 0, 0, 0);
                acc[i][j] = __builtin_amdgcn_mfma_f32_16x16x32_bf16(af[i][1], bfr[j][1], acc[i][j], 0, 0, 0);
            }
    }

    float bias[4];
    #pragma unroll
    for (int j = 0; j < 4; j++) bias[j] = bo[nbase + wn * 64 + j * 16 + ln];

    #pragma unroll
    for (int i = 0; i < 4; i++)
        #pragma unroll
        for (int r = 0; r < 4; r++) {
            int m = mblk * 128 + wm * 64 + i * 16 + quad * 4 + r;
            #pragma unroll
            for (int j = 0; j < 4; j++) {
                int n = nbase + wn * 64 + j * 16 + ln;
                out[(size_t)m * HIDDEN + n] = acc[i][j][r] + bias[j];
            }
        }
}

// ---------------------------------------------------------------------------
extern "C" void kernel_launch(void* const* d_in, const int* in_sizes, int n_in,
                              void* d_out, int out_size, void* d_ws, size_t ws_size,
                              hipStream_t stream)
{
    const float* X    = (const float*)d_in[0];
    const float* cosT = (const float*)d_in[1];
    const float* sinT = (const float*)d_in[2];
    const float* Wq   = (const float*)d_in[3];
    const float* bq   = (const float*)d_in[4];
    const float* Wk   = (const float*)d_in[5];
    const float* bk   = (const float*)d_in[6];
    const float* Wv   = (const float*)d_in[7];
    const float* bv   = (const float*)d_in[8];
    const float* Wo   = (const float*)d_in[9];
    const float* bo   = (const float*)d_in[10];
    float* out = (float*)d_out;

    U16* wsb = (U16*)d_ws;
    U16* Xb  = wsb + OFF_XB;
    U16* Wqb = wsb + OFF_WQB;
    U16* Wkb = wsb + OFF_WKB;
    U16* Wvb = wsb + OFF_WVB;
    U16* Wob = wsb + OFF_WOB;
    U16* qws = wsb + OFF_Q;
    U16* kws = wsb + OFF_K;
    U16* vws = wsb + OFF_V;
    U16* aws = wsb + OFF_AWS;

    conv_kernel<<<dim3(10752), 256, 0, stream>>>(X, Wq, Wk, Wv, Wo, wsb);
    qkv_kernel<<<dim3(12, 64), 256, 0, stream>>>(Xb, Wqb, Wkb, Wvb, bq, bk, bv, cosT, sinT, qws, kws, vws);
    attn_kernel<<<dim3(16, 64), 256, 0, stream>>>(qws, kws, vws, aws);
    proj_kernel<<<dim3(8, 64), 256, 0, stream>>>(aws, Wob, bo, out);
}

// Round 5
// 312.040 us; speedup vs baseline: 1.3268x; 1.3268x over previous
//
#include <hip/hip_runtime.h>
#include <stdint.h>

#define S_LEN 2048
#define HIDDEN 1024
#define NHEADS 16
#define NKVH 4
#define HDIM 64

typedef __bf16 bf16x8 __attribute__((ext_vector_type(8)));
typedef float f32x4 __attribute__((ext_vector_type(4)));
typedef unsigned short ushortx8 __attribute__((ext_vector_type(8)));
typedef short s16x4 __attribute__((ext_vector_type(4)));
typedef unsigned short U16;

// ---- workspace layout (bf16 elems) -----------------------------------------
#define OFF_XB   0u          // 8192*1024 (aliased by aws later)
#define OFF_WQB  8388608u
#define OFF_WKB  9437184u
#define OFF_WVB  9699328u
#define OFF_WOB  9961472u
#define OFF_Q    11010048u
#define OFF_K    19398656u
#define OFF_V    21495808u
#define OFF_AWS  OFF_XB

static __device__ __forceinline__ U16 f2bf(float f){
    unsigned u;
    __builtin_memcpy(&u, &f, 4);
    u += 0x7FFFu + ((u >> 16) & 1u);   // RNE
    return (U16)(u >> 16);
}
static __device__ __forceinline__ uint32_t pkbf(float lo, float hi){
    uint32_t a, b;
    __builtin_memcpy(&a, &lo, 4); a += 0x7FFFu + ((a >> 16) & 1u);
    __builtin_memcpy(&b, &hi, 4); b += 0x7FFFu + ((b >> 16) & 1u);
    return (a >> 16) | (b & 0xFFFF0000u);
}

typedef __attribute__((address_space(3))) uint32_t lds_u32;
typedef const __attribute__((address_space(1))) uint32_t glb_u32;
static __device__ __forceinline__ void glds16(const U16* g, U16* l){
    __builtin_amdgcn_global_load_lds((glb_u32*)g, (lds_u32*)l, 16, 0, 0);
}

// ---------------------------------------------------------------------------
// Kernel 0: fp32 -> bf16 convert of X, Wq, Wk, Wv, Wo into workspace.
// ---------------------------------------------------------------------------
__global__ void conv_kernel(const float* __restrict__ X,  const float* __restrict__ Wq,
                            const float* __restrict__ Wk, const float* __restrict__ Wv,
                            const float* __restrict__ Wo, U16* __restrict__ dst)
{
    size_t i4 = (size_t)blockIdx.x * 256 + threadIdx.x;
    size_t e = i4 * 4;
    const float* s;
    if (e < 8388608u)       s = X  + e;
    else if (e < 9437184u)  s = Wq + (e - 8388608u);
    else if (e < 9699328u)  s = Wk + (e - 9437184u);
    else if (e < 9961472u)  s = Wv + (e - 9699328u);
    else                    s = Wo + (e - 9961472u);
    float4 v = *(const float4*)s;
    uint2 o; o.x = pkbf(v.x, v.y); o.y = pkbf(v.z, v.w);
    *(uint2*)(dst + e) = o;
}

// ---------------------------------------------------------------------------
// Kernel 1: QKV GEMM (NT) + bias + RoPE. BK=64, glds16 staging with XOR
// chunk-swizzle (conflict-free ds_read_b128 on unpadded stride-64 rows).
// Q pre-scaled by 0.125*log2(e) (attention softmax in exp2 domain).
// ---------------------------------------------------------------------------
__global__ __launch_bounds__(256, 3)
void qkv_kernel(const U16* __restrict__ Xb,
                const U16* __restrict__ Wqb, const U16* __restrict__ Wkb, const U16* __restrict__ Wvb,
                const float* __restrict__ bq, const float* __restrict__ bk, const float* __restrict__ bv,
                const float* __restrict__ cosT, const float* __restrict__ sinT,
                U16* __restrict__ qws, U16* __restrict__ kws, U16* __restrict__ vws)
{
    __shared__ __align__(16) U16 Asm[128 * 64];   // 16 KB, unpadded (glds dest)
    __shared__ __align__(16) U16 Bsm[128 * 64];

    const int nblk = blockIdx.x;
    const int mblk = blockIdx.y;
    const int tid  = threadIdx.x;
    const int wave = tid >> 6, lane = tid & 63;
    const int ln = lane & 15, quad = lane >> 4;
    const int wm = wave >> 1, wn = wave & 1;

    const U16* Wp; const float* biasp; int region;
    const int nbase = nblk * 128;
    if (nblk < 8)       { Wp = Wqb + (size_t)nbase * HIDDEN;          biasp = bq + nbase;          region = 0; }
    else if (nblk < 10) { Wp = Wkb + (size_t)(nbase - 1024) * HIDDEN; biasp = bk + (nbase - 1024); region = 1; }
    else                { Wp = Wvb + (size_t)(nbase - 1280) * HIDDEN; biasp = bv + (nbase - 1280); region = 2; }
    const U16* Xp = Xb + (size_t)mblk * 128 * HIDDEN;

    f32x4 acc[4][4];
    #pragma unroll
    for (int i = 0; i < 4; i++)
        #pragma unroll
        for (int j = 0; j < 4; j++) acc[i][j] = (f32x4){0.f, 0.f, 0.f, 0.f};

    const int l8 = lane >> 3;                 // row within 8-row chunk
    const int cg = (lane & 7) ^ l8;           // swizzled global col-chunk
    const int sw = ln & 7;                    // read-side swizzle key

    for (int k0 = 0; k0 < HIDDEN; k0 += 64) {
        __syncthreads();
        #pragma unroll
        for (int t = 0; t < 4; t++) {
            int rbase = wave * 32 + t * 8;
            glds16(Xp + (size_t)(rbase + l8) * HIDDEN + k0 + cg * 8, &Asm[rbase * 64]);
            glds16(Wp + (size_t)(rbase + l8) * HIDDEN + k0 + cg * 8, &Bsm[rbase * 64]);
        }
        __syncthreads();

        bf16x8 af[4][2], bfr[4][2];
        #pragma unroll
        for (int i = 0; i < 4; i++)
            #pragma unroll
            for (int ks = 0; ks < 2; ks++) {
                af[i][ks]  = *(const bf16x8*)(&Asm[(wm * 64 + i * 16 + ln) * 64 + (((ks * 4 + quad) ^ sw) * 8)]);
                bfr[i][ks] = *(const bf16x8*)(&Bsm[(wn * 64 + i * 16 + ln) * 64 + (((ks * 4 + quad) ^ sw) * 8)]);
            }
        #pragma unroll
        for (int i = 0; i < 4; i++)
            #pragma unroll
            for (int j = 0; j < 4; j++) {
                acc[i][j] = __builtin_amdgcn_mfma_f32_16x16x32_bf16(af[i][0], bfr[j][0], acc[i][j], 0, 0, 0);
                acc[i][j] = __builtin_amdgcn_mfma_f32_16x16x32_bf16(af[i][1], bfr[j][1], acc[i][j], 0, 0, 0);
            }
    }

    float bias[4];
    #pragma unroll
    for (int j = 0; j < 4; j++) bias[j] = biasp[wn * 64 + j * 16 + ln];

    const float QSCALE = 0.125f * 1.44269504089f;

    #pragma unroll
    for (int i = 0; i < 4; i++) {
        #pragma unroll
        for (int r = 0; r < 4; r++) {
            int m = mblk * 128 + wm * 64 + i * 16 + quad * 4 + r;
            int s = m & (S_LEN - 1), b = m >> 11;
            float vals[4];
            #pragma unroll
            for (int j = 0; j < 4; j++) vals[j] = acc[i][j][r] + bias[j];

            if (region == 2) {      // V
                #pragma unroll
                for (int j = 0; j < 4; j++) {
                    int n2 = nbase - 1280 + wn * 64 + j * 16 + ln;
                    int hh = n2 >> 6, d = n2 & 63;
                    vws[(((size_t)b * NKVH + hh) * S_LEN + s) * HDIM + d] = f2bf(vals[j]);
                }
            } else {
                float outv[4];
                #pragma unroll
                for (int j = 0; j < 4; j++) {
                    int d = (wn * 64 + j * 16 + ln) & 63;
                    float c  = cosT[s * HDIM + d];
                    float sn = sinT[s * HDIM + d];
                    float partner = vals[j ^ 2];
                    float rot = (d < 32) ? -partner : partner;
                    outv[j] = vals[j] * c + rot * sn;
                }
                if (region == 0) {  // Q (scaled)
                    #pragma unroll
                    for (int j = 0; j < 4; j++) {
                        int n = nbase + wn * 64 + j * 16 + ln;
                        int hh = n >> 6, d = n & 63;
                        qws[(((size_t)b * NHEADS + hh) * S_LEN + s) * HDIM + d] = f2bf(outv[j] * QSCALE);
                    }
                } else {            // K
                    #pragma unroll
                    for (int j = 0; j < 4; j++) {
                        int n2 = nbase - 1024 + wn * 64 + j * 16 + ln;
                        int hh = n2 >> 6, d = n2 & 63;
                        kws[(((size_t)b * NKVH + hh) * S_LEN + s) * HDIM + d] = f2bf(outv[j]);
                    }
                }
            }
        }
    }
}

// ---------------------------------------------------------------------------
// Kernel 2: flash attention. 64-key tiles, fully double-buffered:
//   K staged via global_load_lds (XOR-swizzled, conflict-free b128 reads),
//   V^T staged via reg->LDS transpose scatter. ONE barrier per tile.
// S^T = K*Q^T (16x16x32); PV via 16x16x16: packed scores ARE the B-frag.
// LDS 34.8 KB -> 4 blocks/CU. grid (16, 64).
// ---------------------------------------------------------------------------
#define A_VTS 72

__global__ __launch_bounds__(256, 4)
void attn_kernel(const U16* __restrict__ qws, const U16* __restrict__ kws,
                 const U16* __restrict__ vws, U16* __restrict__ aws)
{
    __shared__ __align__(16) U16 Ksm[2][64 * 64];     // 16 KB
    __shared__ __align__(16) U16 VTsm[2][64 * A_VTS]; // 18 KB

    const int qt = blockIdx.x;
    const int hg = blockIdx.y;
    const int b = hg >> 4, h = hg & 15, hkv = h >> 2;
    const U16* Qh = qws + (size_t)hg * S_LEN * HDIM;
    const U16* Kh = kws + (size_t)(b * NKVH + hkv) * S_LEN * HDIM;
    const U16* Vh = vws + (size_t)(b * NKVH + hkv) * S_LEN * HDIM;

    const int tid = threadIdx.x;
    const int wave = tid >> 6, lane = tid & 63;
    const int ln = lane & 15, quad = lane >> 4;
    const int sw = ln & 7;                    // read-side swizzle key

    // Q fragments (B-operand, resident): q = qt*128 + wave*32 + 16i + ln
    bf16x8 qf[2][2];
    #pragma unroll
    for (int i = 0; i < 2; i++)
        #pragma unroll
        for (int ks = 0; ks < 2; ks++) {
            int row = qt * 128 + wave * 32 + i * 16 + ln;
            qf[i][ks] = *(const bf16x8*)(Qh + (size_t)row * HDIM + ks * 32 + quad * 8);
        }

    float mi[2] = {-1e30f, -1e30f}, li[2] = {0.f, 0.f};
    f32x4 o_t[4][2];
    #pragma unroll
    for (int n = 0; n < 4; n++)
        #pragma unroll
        for (int i = 0; i < 2; i++) o_t[n][i] = (f32x4){0.f, 0.f, 0.f, 0.f};

    // K glds addressing: wave covers chunks c = wave*2 + t (8 rows each)
    const int l8 = lane >> 3;
    const int cgk = (lane & 7) ^ l8;          // swizzled global chunk

    // prologue: K tile 0 via glds, V tile 0 into regs
    #pragma unroll
    for (int t = 0; t < 2; t++) {
        int c = wave * 2 + t;
        glds16(Kh + (size_t)(c * 8 + l8) * HDIM + cgk * 8, &Ksm[0][c * 8 * 64]);
    }
    ushortx8 vreg[2];
    #pragma unroll
    for (int it = 0; it < 2; it++) {
        int idx = tid + it * 256;
        vreg[it] = *(const ushortx8*)(Vh + (size_t)(idx & 63) * HDIM + ((idx >> 6) * 8));
    }

    int p = 0;
    for (int kt = 0; kt < 32; kt++) {
        // V^T scatter into current buffer
        #pragma unroll
        for (int it = 0; it < 2; it++) {
            int idx = tid + it * 256;
            int sv = idx & 63, d0 = (idx >> 6) * 8;
            #pragma unroll
            for (int jj = 0; jj < 8; jj++) VTsm[p][(d0 + jj) * A_VTS + sv] = vreg[it][jj];
        }
        __syncthreads();   // drains glds (Ksm[p] ready) + VTsm[p] visible

        // prefetch next tile (flies under this tile's compute)
        if (kt < 31) {
            #pragma unroll
            for (int t = 0; t < 2; t++) {
                int c = wave * 2 + t;
                glds16(Kh + (size_t)((kt + 1) * 64 + c * 8 + l8) * HDIM + cgk * 8, &Ksm[p ^ 1][c * 8 * 64]);
            }
            #pragma unroll
            for (int it = 0; it < 2; it++) {
                int idx = tid + it * 256;
                vreg[it] = *(const ushortx8*)(Vh + (size_t)((kt + 1) * 64 + (idx & 63)) * HDIM + ((idx >> 6) * 8));
            }
        }

        // ---- S^T = K*Q^T (64 keys, 4 j-blocks)
        f32x4 st[2][4];
        #pragma unroll
        for (int j4 = 0; j4 < 4; j4++) {
            int row = j4 * 16 + ln;
            bf16x8 kf0 = *(const bf16x8*)(&Ksm[p][row * 64 + ((quad ^ sw) * 8)]);
            bf16x8 kf1 = *(const bf16x8*)(&Ksm[p][row * 64 + (((quad + 4) ^ sw) * 8)]);
            #pragma unroll
            for (int i = 0; i < 2; i++) {
                f32x4 z = (f32x4){0.f, 0.f, 0.f, 0.f};
                z = __builtin_amdgcn_mfma_f32_16x16x32_bf16(kf0, qf[i][0], z, 0, 0, 0);
                z = __builtin_amdgcn_mfma_f32_16x16x32_bf16(kf1, qf[i][1], z, 0, 0, 0);
                st[i][j4] = z;
            }
        }

        // ---- online softmax (exp2 domain; per-lane rows q = 16i+ln)
        uint32_t pk[2][4][2];
        #pragma unroll
        for (int i = 0; i < 2; i++) {
            float v = st[i][0][0];
            #pragma unroll
            for (int j4 = 0; j4 < 4; j4++)
                #pragma unroll
                for (int r = 0; r < 4; r++) v = fmaxf(v, st[i][j4][r]);
            v = fmaxf(v, __shfl_xor(v, 16));
            v = fmaxf(v, __shfl_xor(v, 32));
            float mnew = fmaxf(mi[i], v);
            float alpha = __builtin_amdgcn_exp2f(mi[i] - mnew);
            mi[i] = mnew;
            float rs = 0.f;
            #pragma unroll
            for (int j4 = 0; j4 < 4; j4++)
                #pragma unroll
                for (int r = 0; r < 4; r++) {
                    float pv = __builtin_amdgcn_exp2f(st[i][j4][r] - mnew);
                    st[i][j4][r] = pv;
                    rs += pv;
                }
            rs += __shfl_xor(rs, 16);
            rs += __shfl_xor(rs, 32);
            li[i] = li[i] * alpha + rs;
            #pragma unroll
            for (int n = 0; n < 4; n++) o_t[n][i] *= alpha;
            #pragma unroll
            for (int j4 = 0; j4 < 4; j4++) {
                pk[i][j4][0] = pkbf(st[i][j4][0], st[i][j4][1]);
                pk[i][j4][1] = pkbf(st[i][j4][2], st[i][j4][3]);
            }
        }

        // ---- O^T += V^T * P^T via 16x16x16 (B-frag = packed scores)
        #pragma unroll
        for (int j4 = 0; j4 < 4; j4++) {
            s16x4 pf[2];
            #pragma unroll
            for (int i = 0; i < 2; i++) __builtin_memcpy(&pf[i], pk[i][j4], 8);
            #pragma unroll
            for (int n = 0; n < 4; n++) {
                s16x4 vf = *(const s16x4*)(&VTsm[p][(n * 16 + ln) * A_VTS + j4 * 16 + quad * 4]);
                #pragma unroll
                for (int i = 0; i < 2; i++)
                    o_t[n][i] = __builtin_amdgcn_mfma_f32_16x16x16bf16_1k(vf, pf[i], o_t[n][i], 0, 0, 0);
            }
        }
        p ^= 1;
    }

    // epilogue: normalize, write O (8B stores)
    float inv_li[2] = {1.f / li[0], 1.f / li[1]};
    #pragma unroll
    for (int n = 0; n < 4; n++)
        #pragma unroll
        for (int i = 0; i < 2; i++) {
            int q = qt * 128 + wave * 32 + i * 16 + ln;
            int d = n * 16 + quad * 4;
            uint2 w;
            w.x = pkbf(o_t[n][i][0] * inv_li[i], o_t[n][i][1] * inv_li[i]);
            w.y = pkbf(o_t[n][i][2] * inv_li[i], o_t[n][i][3] * inv_li[i]);
            *(uint2*)(aws + ((size_t)b * S_LEN + q) * (NHEADS * HDIM) + h * HDIM + d) = w;
        }
}

// ---------------------------------------------------------------------------
// Kernel 3: output projection GEMM (NT) + bias. BK=64, swizzled. fp32 out.
// ---------------------------------------------------------------------------
__global__ __launch_bounds__(256, 3)
void proj_kernel(const U16* __restrict__ A, const U16* __restrict__ Wob,
                 const float* __restrict__ bo, float* __restrict__ out)
{
    __shared__ __align__(16) U16 Asm[128 * 64];
    __shared__ __align__(16) U16 Bsm[128 * 64];

    const int nblk = blockIdx.x;
    const int mblk = blockIdx.y;
    const int tid  = threadIdx.x;
    const int wave = tid >> 6, lane = tid & 63;
    const int ln = lane & 15, quad = lane >> 4;
    const int wm = wave >> 1, wn = wave & 1;

    const int nbase = nblk * 128;
    const U16* Wp = Wob + (size_t)nbase * HIDDEN;
    const U16* Ap = A + (size_t)mblk * 128 * HIDDEN;

    f32x4 acc[4][4];
    #pragma unroll
    for (int i = 0; i < 4; i++)
        #pragma unroll
        for (int j = 0; j < 4; j++) acc[i][j] = (f32x4){0.f, 0.f, 0.f, 0.f};

    const int l8 = lane >> 3;
    const int cg = (lane & 7) ^ l8;
    const int sw = ln & 7;

    for (int k0 = 0; k0 < HIDDEN; k0 += 64) {
        __syncthreads();
        #pragma unroll
        for (int t = 0; t < 4; t++) {
            int rbase = wave * 32 + t * 8;
            glds16(Ap + (size_t)(rbase + l8) * HIDDEN + k0 + cg * 8, &Asm[rbase * 64]);
            glds16(Wp + (size_t)(rbase + l8) * HIDDEN + k0 + cg * 8, &Bsm[rbase * 64]);
        }
        __syncthreads();

        bf16x8 af[4][2], bfr[4][2];
        #pragma unroll
        for (int i = 0; i < 4; i++)
            #pragma unroll
            for (int ks = 0; ks < 2; ks++) {
                af[i][ks]  = *(const bf16x8*)(&Asm[(wm * 64 + i * 16 + ln) * 64 + (((ks * 4 + quad) ^ sw) * 8)]);
                bfr[i][ks] = *(const bf16x8*)(&Bsm[(wn * 64 + i * 16 + ln) * 64 + (((ks * 4 + quad) ^ sw) * 8)]);
            }
        #pragma unroll
        for (int i = 0; i < 4; i++)
            #pragma unroll
            for (int j = 0; j < 4; j++) {
                acc[i][j] = __builtin_amdgcn_mfma_f32_16x16x32_bf16(af[i][0], bfr[j][0], acc[i][j], 0, 0, 0);
                acc[i][j] = __builtin_amdgcn_mfma_f32_16x16x32_bf16(af[i][1], bfr[j][1], acc[i][j], 0, 0, 0);
            }
    }

    float bias[4];
    #pragma unroll
    for (int j = 0; j < 4; j++) bias[j] = bo[nbase + wn * 64 + j * 16 + ln];

    #pragma unroll
    for (int i = 0; i < 4; i++)
        #pragma unroll
        for (int r = 0; r < 4; r++) {
            int m = mblk * 128 + wm * 64 + i * 16 + quad * 4 + r;
            #pragma unroll
            for (int j = 0; j < 4; j++) {
                int n = nbase + wn * 64 + j * 16 + ln;
                out[(size_t)m * HIDDEN + n] = acc[i][j][r] + bias[j];
            }
        }
}

// ---------------------------------------------------------------------------
extern "C" void kernel_launch(void* const* d_in, const int* in_sizes, int n_in,
                              void* d_out, int out_size, void* d_ws, size_t ws_size,
                              hipStream_t stream)
{
    const float* X    = (const float*)d_in[0];
    const float* cosT = (const float*)d_in[1];
    const float* sinT = (const float*)d_in[2];
    const float* Wq   = (const float*)d_in[3];
    const float* bq   = (const float*)d_in[4];
    const float* Wk   = (const float*)d_in[5];
    const float* bk   = (const float*)d_in[6];
    const float* Wv   = (const float*)d_in[7];
    const float* bv   = (const float*)d_in[8];
    const float* Wo   = (const float*)d_in[9];
    const float* bo   = (const float*)d_in[10];
    float* out = (float*)d_out;

    U16* wsb = (U16*)d_ws;
    U16* Xb  = wsb + OFF_XB;
    U16* Wqb = wsb + OFF_WQB;
    U16* Wkb = wsb + OFF_WKB;
    U16* Wvb = wsb + OFF_WVB;
    U16* Wob = wsb + OFF_WOB;
    U16* qws = wsb + OFF_Q;
    U16* kws = wsb + OFF_K;
    U16* vws = wsb + OFF_V;
    U16* aws = wsb + OFF_AWS;

    conv_kernel<<<dim3(10752), 256, 0, stream>>>(X, Wq, Wk, Wv, Wo, wsb);
    qkv_kernel<<<dim3(12, 64), 256, 0, stream>>>(Xb, Wqb, Wkb, Wvb, bq, bk, bv, cosT, sinT, qws, kws, vws);
    attn_kernel<<<dim3(16, 64), 256, 0, stream>>>(qws, kws, vws, aws);
    proj_kernel<<<dim3(8, 64), 256, 0, stream>>>(aws, Wob, bo, out);
}